// Round 7
// baseline (269.595 us; speedup 1.0000x reference)
//
#include <hip/hip_runtime.h>

#define NPTS 8192
#define DIM 64
#define BATCH 2
#define KOUT 17
#define QCAP 44     // queue capacity per (row, seg)
#define THRANK 21   // theta = 22nd smallest of the 64-subset

typedef float f32x4 __attribute__((ext_vector_type(4)));
typedef float f32x16 __attribute__((ext_vector_type(16)));
typedef short short8 __attribute__((ext_vector_type(8)));
typedef unsigned int uint4v __attribute__((ext_vector_type(4)));

__device__ __forceinline__ void gload16(const void* g, void* lds) {
  __builtin_amdgcn_global_load_lds((const __attribute__((address_space(1))) void*)g,
                                   (__attribute__((address_space(3))) void*)lds, 16, 0, 0);
}

// ---------- prep: permuted hi/lo bf16 (phl), contiguous f32 (pct), 0.5*|x|^2 ----------
__global__ __launch_bounds__(256)
void prep_kernel(const float* __restrict__ pc, ushort* __restrict__ phl,
                 float* __restrict__ pct, float* __restrict__ sq) {
  __shared__ double psum[256];
  int t = threadIdx.x;
  int u = t >> 5;           // 0..7  (dims u*8 .. u*8+7)
  int p = t & 31;           // 0..31 (point within block)
  int i = blockIdx.x * 32 + p;   // 0..16383
  int b = i >> 13, n = i & (NPTS - 1);
  const float* g = pc + (size_t)b * DIM * NPTS + n;

  float x[8];
  short8 hv, lv;
  double s = 0.0;
  #pragma unroll
  for (int e = 0; e < 8; ++e) {
    x[e] = g[(size_t)(u * 8 + e) * NPTS];
    s += (double)x[e] * (double)x[e];
    unsigned uu = __float_as_uint(x[e]);
    unsigned r = uu + (0x7fffu + ((uu >> 16) & 1));
    unsigned hi = r >> 16;                       // bf16 RNE
    float xl = x[e] - __uint_as_float(hi << 16);
    unsigned ul = __float_as_uint(xl);
    unsigned rl = ul + (0x7fffu + ((ul >> 16) & 1));
    hv[e] = (short)(hi & 0xffffu);
    lv[e] = (short)((rl >> 16) & 0xffffu);
  }
  int slot = u ^ (n & 7);
  ushort* ph = phl + (size_t)i * 128;
  *(short8*)(ph + slot * 8) = hv;
  *(short8*)(ph + 64 + slot * 8) = lv;
  f32x4 v0 = {x[0], x[1], x[2], x[3]}, v1 = {x[4], x[5], x[6], x[7]};
  *(f32x4*)(pct + (size_t)i * 64 + u * 8) = v0;
  *(f32x4*)(pct + (size_t)i * 64 + u * 8 + 4) = v1;

  psum[u * 32 + p] = s;
  __syncthreads();
  if (t < 32) {
    double acc = 0.0;
    #pragma unroll
    for (int uu = 0; uu < 8; ++uu) acc += psum[uu * 32 + t];
    sq[blockIdx.x * 32 + t] = (float)(0.5 * acc);   // HALF |x|^2
  }
}

// ---------- two-pass 32x32 MFMA distance + theta-filter collect ----------
// 1024 blocks x 256 threads; block = (b, seg, rowgroup): 32 rows x 4096 cols (32 tiles of 128).
// key(row,col) = 0.5*|col|^2 - <row,col>. C layout: col = lane&31, row = (r&3)+8*(r>>2)+4*(lane>>5).
__global__ __launch_bounds__(256, 4)
void knn_kernel(const ushort* __restrict__ phl, const float* __restrict__ sq,
                ushort* __restrict__ cand) {
  __shared__ ushort Bt[128 * 128];  // 32 KB; aliased WK/SUBS between passes
  __shared__ float TH[32];
  __shared__ int CNT[32];
  __shared__ ushort QU[32][QCAP];

  int t = threadIdx.x;
  int lane = t & 63;
  int w = t >> 6;
  int b = blockIdx.x >> 9;
  int seg = (blockIdx.x >> 8) & 1;
  int row0 = (blockIdx.x & 255) * 32;
  const ushort* pb = phl + (size_t)b * NPTS * 128;
  const float* sqb = sq + b * NPTS;

  int p31 = lane & 31, l5 = lane >> 5;
  int ccol = w * 32;

  // A fragments (row = row0+p31, chunk 2ks+l5 per hi/lo), sign-flipped (exact)
  short8 a[2][4];   // [hl][ks]
  {
    int n = row0 + p31;
    const ushort* pr = pb + (size_t)n * 128;
    #pragma unroll
    for (int hl = 0; hl < 2; ++hl)
      #pragma unroll
      for (int ks = 0; ks < 4; ++ks) {
        int slot = (2 * ks + l5) ^ (n & 7);
        short8 v = *(const short8*)(pr + hl * 64 + slot * 8);
        uint4v uv = *(uint4v*)&v;
        uv ^= 0x80008000u;
        a[hl][ks] = *(short8*)&uv;
      }
  }

  // ================= PASS A: per-lane top-2 per owned row (16 rows/lane) =================
  float k1[16], k2[16];
  #pragma unroll
  for (int r = 0; r < 16; ++r) { k1[r] = __builtin_inff(); k2[r] = __builtin_inff(); }

  for (int tile = 0; tile < 32; ++tile) {
    int n0 = (seg * 32 + tile) * 128;
    __syncthreads();
    #pragma unroll
    for (int j = 0; j < 8; ++j) {
      const ushort* src = pb + (size_t)(n0 + w * 32 + j * 4 + (lane >> 4)) * 128 + (lane & 15) * 8;
      gload16(src, Bt + (w * 32 + j * 4) * 128);
    }
    float sqv = sqb[n0 + ccol + p31];
    __syncthreads();

    int p = ccol + p31;
    const ushort* bp = Bt + p * 128;
    int sw = p & 7;
    f32x16 c;
    #pragma unroll
    for (int i = 0; i < 16; ++i) c[i] = sqv;
    #pragma unroll
    for (int ks = 0; ks < 4; ++ks) {
      int so = ((2 * ks + l5) ^ sw) * 8;
      short8 bh = *(const short8*)(bp + so);
      short8 bl = *(const short8*)(bp + 64 + so);
      c = __builtin_amdgcn_mfma_f32_32x32x16_bf16(a[0][ks], bh, c, 0, 0, 0);
      c = __builtin_amdgcn_mfma_f32_32x32x16_bf16(a[0][ks], bl, c, 0, 0, 0);
      c = __builtin_amdgcn_mfma_f32_32x32x16_bf16(a[1][ks], bh, c, 0, 0, 0);
    }
    #pragma unroll
    for (int r = 0; r < 16; ++r) {
      k2[r] = __builtin_amdgcn_fmed3f(c[r], k1[r], k2[r]);
      k1[r] = fminf(c[r], k1[r]);
    }
  }

  // ================= build 64-value subset per row via cross-wave pointwise min =================
  __syncthreads();
  float* WK = (float*)Bt;   // [4 waves][64 lanes][32]: k1[16] | k2[16]
  {
    int base = (w * 64 + lane) * 32;
    #pragma unroll
    for (int r = 0; r < 16; ++r) { WK[base + r] = k1[r]; WK[base + 16 + r] = k2[r]; }
  }
  __syncthreads();
  float red[8];
  {
    int j = t & 31, rr = t >> 5;   // rr 0..7
    #pragma unroll
    for (int i2 = 0; i2 < 2; ++i2) {
      int r16 = rr * 2 + i2;
      #pragma unroll
      for (int h = 0; h < 2; ++h) {
        int li = j + 32 * h;
        float m1 = WK[(0 * 64 + li) * 32 + r16];
        float m2 = WK[(0 * 64 + li) * 32 + 16 + r16];
        #pragma unroll
        for (int ww = 1; ww < 4; ++ww) {
          m1 = fminf(m1, WK[(ww * 64 + li) * 32 + r16]);
          m2 = fminf(m2, WK[(ww * 64 + li) * 32 + 16 + r16]);
        }
        red[i2 * 4 + h * 2 + 0] = m1;
        red[i2 * 4 + h * 2 + 1] = m2;
      }
    }
  }
  __syncthreads();
  float* SUBS = (float*)Bt;   // [32][64]
  {
    int j = t & 31, rr = t >> 5;
    #pragma unroll
    for (int i2 = 0; i2 < 2; ++i2) {
      int r16 = rr * 2 + i2;
      #pragma unroll
      for (int h = 0; h < 2; ++h) {
        int row = (r16 & 3) + 8 * (r16 >> 2) + 4 * h;
        SUBS[row * 64 + 2 * j] = red[i2 * 4 + h * 2 + 0];
        SUBS[row * 64 + 2 * j + 1] = red[i2 * 4 + h * 2 + 1];
      }
    }
  }
  __syncthreads();

  // ================= theta per row = 22nd smallest of 64-subset =================
  {
    int row = t >> 3;
    int j0 = (t & 7) * 8;
    const f32x4* vr4 = (const f32x4*)(SUBS + row * 64);
    float vj[8];
    *(f32x4*)vj = vr4[(t & 7) * 2];
    *(f32x4*)(vj + 4) = vr4[(t & 7) * 2 + 1];
    int rank[8];
    #pragma unroll
    for (int jj = 0; jj < 8; ++jj) rank[jj] = 0;
    for (int m4 = 0; m4 < 16; ++m4) {
      f32x4 vm = vr4[m4];
      #pragma unroll
      for (int e = 0; e < 4; ++e) {
        int m = m4 * 4 + e;
        float ve = vm[e];
        #pragma unroll
        for (int jj = 0; jj < 8; ++jj)
          rank[jj] += (ve < vj[jj] || (ve == vj[jj] && m < j0 + jj)) ? 1 : 0;
      }
    }
    #pragma unroll
    for (int jj = 0; jj < 8; ++jj)
      if (rank[jj] == THRANK) TH[row] = vj[jj];
    if (t < 32) CNT[t] = 0;
  }
  __syncthreads();
  float th[16];
  #pragma unroll
  for (int r = 0; r < 16; ++r) th[r] = TH[(r & 3) + 8 * (r >> 2) + 4 * l5];

  // ================= PASS B: recompute + collect key<=theta =================
  for (int tile = 0; tile < 32; ++tile) {
    int n0 = (seg * 32 + tile) * 128;
    __syncthreads();
    #pragma unroll
    for (int j = 0; j < 8; ++j) {
      const ushort* src = pb + (size_t)(n0 + w * 32 + j * 4 + (lane >> 4)) * 128 + (lane & 15) * 8;
      gload16(src, Bt + (w * 32 + j * 4) * 128);
    }
    float sqv = sqb[n0 + ccol + p31];
    __syncthreads();

    int p = ccol + p31;
    const ushort* bp = Bt + p * 128;
    int sw = p & 7;
    f32x16 c;
    #pragma unroll
    for (int i = 0; i < 16; ++i) c[i] = sqv;
    #pragma unroll
    for (int ks = 0; ks < 4; ++ks) {
      int so = ((2 * ks + l5) ^ sw) * 8;
      short8 bh = *(const short8*)(bp + so);
      short8 bl = *(const short8*)(bp + 64 + so);
      c = __builtin_amdgcn_mfma_f32_32x32x16_bf16(a[0][ks], bh, c, 0, 0, 0);
      c = __builtin_amdgcn_mfma_f32_32x32x16_bf16(a[0][ks], bl, c, 0, 0, 0);
      c = __builtin_amdgcn_mfma_f32_32x32x16_bf16(a[1][ks], bh, c, 0, 0, 0);
    }
    #pragma unroll
    for (int r = 0; r < 16; ++r) {
      if (c[r] <= th[r]) {
        int row = (r & 3) + 8 * (r >> 2) + 4 * l5;
        int pos = atomicAdd(&CNT[row], 1);
        if (pos < QCAP) QU[row][pos] = (ushort)(n0 + ccol + p31);
      }
    }
  }

  // ================= pad + dump queues =================
  __syncthreads();
  for (int i = t; i < 32 * QCAP; i += 256) {
    int row = i / QCAP, s2 = i % QCAP;
    int c2 = CNT[row]; if (c2 > QCAP) c2 = QCAP;
    ushort v = (s2 < c2) ? QU[row][s2] : (ushort)0xFFFFu;
    cand[((size_t)(b * NPTS + row0 + row) * 2 + seg) * QCAP + s2] = v;
  }
}

// ---------- exact f64 re-rank of up to 88 candidates, wave per point ----------
__global__ void refine_kernel(const float* __restrict__ pct, const ushort* __restrict__ cand,
                              int* __restrict__ knn, float* __restrict__ idxf) {
  int gw = (blockIdx.x * 256 + threadIdx.x) >> 6;  // 0..16383
  int lane = threadIdx.x & 63;
  int b = gw >> 13, n = gw & (NPTS - 1);
  const float* pcb = pct + (size_t)b * NPTS * 64;
  const ushort* cb = cand + (size_t)gw * (2 * QCAP);
  const float* qp = pcb + (size_t)n * 64;

  unsigned ciA = cb[lane];
  unsigned ciB = (lane < 2 * QCAP - 64) ? (unsigned)cb[64 + lane] : 0xFFFFu;
  double dA = __builtin_inf(), dB = __builtin_inf();
  if (ciA != 0xFFFFu) {
    const float* cp = pcb + (size_t)ciA * 64;
    double s = 0.0;
    #pragma unroll
    for (int u = 0; u < 16; ++u) {
      f32x4 cv = *(const f32x4*)(cp + u * 4);
      f32x4 qv = *(const f32x4*)(qp + u * 4);
      #pragma unroll
      for (int e = 0; e < 4; ++e) {
        double diff = (double)cv[e] - (double)qv[e];
        s = fma(diff, diff, s);
      }
    }
    dA = s;
  }
  if (ciB != 0xFFFFu) {
    const float* cp = pcb + (size_t)ciB * 64;
    double s = 0.0;
    #pragma unroll
    for (int u = 0; u < 16; ++u) {
      f32x4 cv = *(const f32x4*)(cp + u * 4);
      f32x4 qv = *(const f32x4*)(qp + u * 4);
      #pragma unroll
      for (int e = 0; e < 4; ++e) {
        double diff = (double)cv[e] - (double)qv[e];
        s = fma(diff, diff, s);
      }
    }
    dB = s;
  }

  int rA = 0, rB = 0;
  for (int j = 0; j < 64; ++j) {
    double dk = __shfl(dA, j);
    unsigned ik = (unsigned)__shfl((int)ciA, j);
    rA += ((dk < dA) || (dk == dA && ik < ciA)) ? 1 : 0;
    rB += ((dk < dB) || (dk == dB && ik < ciB)) ? 1 : 0;
  }
  for (int j = 0; j < 2 * QCAP - 64; ++j) {
    double dk = __shfl(dB, j);
    unsigned ik = (unsigned)__shfl((int)ciB, j);
    rA += ((dk < dA) || (dk == dA && ik < ciA)) ? 1 : 0;
    rB += ((dk < dB) || (dk == dB && ik < ciB)) ? 1 : 0;
  }
  if (ciA != 0xFFFFu && rA < KOUT) {
    size_t o = ((size_t)b * KOUT + rA) * NPTS + n;
    knn[o] = (int)ciA;
    idxf[o] = (float)ciA;
  }
  if (lane < 2 * QCAP - 64 && ciB != 0xFFFFu && rB < KOUT) {
    size_t o = ((size_t)b * KOUT + rB) * NPTS + n;
    knn[o] = (int)ciB;
    idxf[o] = (float)ciB;
  }
}

// ---------- edge features: out [B][128][17][N]; block = (n-chunk, b*64+c), k-loop inside ----------
__global__ __launch_bounds__(256)
void edge_kernel(const float* __restrict__ pc, const int* __restrict__ knn,
                 float* __restrict__ out) {
  int n = blockIdx.x * 256 + threadIdx.x;
  int z = blockIdx.y;
  int b = z >> 6, c = z & 63;
  const float* row = pc + ((size_t)b * DIM + c) * NPTS;
  float central = row[n];
  size_t base = (((size_t)b * 2 * DIM + c) * KOUT) * NPTS + n;
  const int* kb = knn + (size_t)b * KOUT * NPTS + n;
  #pragma unroll
  for (int k = 0; k < KOUT; ++k) {
    int nb = kb[(size_t)k * NPTS];
    float nbrv = row[nb];
    out[base + (size_t)k * NPTS] = central;
    out[base + (size_t)(DIM * KOUT + k) * NPTS] = nbrv - central;
  }
}

extern "C" void kernel_launch(void* const* d_in, const int* in_sizes, int n_in,
                              void* d_out, int out_size, void* d_ws, size_t ws_size,
                              hipStream_t stream) {
  const float* pc = (const float*)d_in[0];
  float* out = (float*)d_out;
  char* ws = (char*)d_ws;
  ushort* phl = (ushort*)ws;                                     // 4 MB
  float* pct  = (float*)(ws + (size_t)4 * 1024 * 1024);          // 4 MB
  float* sq   = (float*)(ws + (size_t)8 * 1024 * 1024);          // 64 KB
  ushort* cand = (ushort*)(ws + (size_t)8 * 1024 * 1024 + 65536);
  int* knn    = (int*)(ws + (size_t)8 * 1024 * 1024 + 65536 + (size_t)16384 * 2 * QCAP * 2);

  float* idxf = out + (size_t)BATCH * 2 * DIM * KOUT * NPTS;

  prep_kernel<<<512, 256, 0, stream>>>(pc, phl, pct, sq);
  knn_kernel<<<1024, 256, 0, stream>>>(phl, sq, cand);
  refine_kernel<<<4096, 256, 0, stream>>>(pct, cand, knn, idxf);
  edge_kernel<<<dim3(NPTS / 256, BATCH * DIM), 256, 0, stream>>>(pc, knn, out);
}

// Round 8
// 240.549 us; speedup vs baseline: 1.1208x; 1.1208x over previous
//
#include <hip/hip_runtime.h>

#define NPTS 8192
#define DIM 64
#define BATCH 2
#define KOUT 17
#define QCAP 40     // queue capacity per (row, seg)
#define THRANK 21   // theta = 22nd smallest of the 64-subset

typedef float f32x4 __attribute__((ext_vector_type(4)));
typedef short short8 __attribute__((ext_vector_type(8)));
typedef unsigned int uint4v __attribute__((ext_vector_type(4)));

__device__ __forceinline__ void gload16(const void* g, void* lds) {
  __builtin_amdgcn_global_load_lds((const __attribute__((address_space(1))) void*)g,
                                   (__attribute__((address_space(3))) void*)lds, 16, 0, 0);
}

// ---------- prep: permuted hi/lo bf16 (phl), contiguous f32 (pct), 0.5*|x|^2 ----------
__global__ __launch_bounds__(256)
void prep_kernel(const float* __restrict__ pc, ushort* __restrict__ phl,
                 float* __restrict__ pct, float* __restrict__ sq) {
  __shared__ double psum[256];
  int t = threadIdx.x;
  int u = t >> 5;           // 0..7  (dims u*8 .. u*8+7)
  int p = t & 31;           // 0..31 (point within block)
  int i = blockIdx.x * 32 + p;   // 0..16383
  int b = i >> 13, n = i & (NPTS - 1);
  const float* g = pc + (size_t)b * DIM * NPTS + n;

  float x[8];
  short8 hv, lv;
  double s = 0.0;
  #pragma unroll
  for (int e = 0; e < 8; ++e) {
    x[e] = g[(size_t)(u * 8 + e) * NPTS];
    s += (double)x[e] * (double)x[e];
    unsigned uu = __float_as_uint(x[e]);
    unsigned r = uu + (0x7fffu + ((uu >> 16) & 1));
    unsigned hi = r >> 16;                       // bf16 RNE
    float xl = x[e] - __uint_as_float(hi << 16);
    unsigned ul = __float_as_uint(xl);
    unsigned rl = ul + (0x7fffu + ((ul >> 16) & 1));
    hv[e] = (short)(hi & 0xffffu);
    lv[e] = (short)((rl >> 16) & 0xffffu);
  }
  int slot = u ^ (n & 7);
  ushort* ph = phl + (size_t)i * 128;
  *(short8*)(ph + slot * 8) = hv;
  *(short8*)(ph + 64 + slot * 8) = lv;
  f32x4 v0 = {x[0], x[1], x[2], x[3]}, v1 = {x[4], x[5], x[6], x[7]};
  *(f32x4*)(pct + (size_t)i * 64 + u * 8) = v0;
  *(f32x4*)(pct + (size_t)i * 64 + u * 8 + 4) = v1;

  psum[u * 32 + p] = s;
  __syncthreads();
  if (t < 32) {
    double acc = 0.0;
    #pragma unroll
    for (int uu = 0; uu < 8; ++uu) acc += psum[uu * 32 + t];
    sq[blockIdx.x * 32 + t] = (float)(0.5 * acc);   // HALF |x|^2
  }
}

// ---------- two-pass MFMA distance + theta-filter collect, 2-rowgroup B-reuse ----------
// 1024 blocks x 256 threads; block = (b, seg, rowgroup): 32 rows x 4096 cols (32 tiles of 128).
// wave w covers cols w*32..w*32+31 (2 cf), ALL 32 rows (2 row-groups of 16).
// key(row,col) = 0.5*|col|^2 - <row,col>
__global__ __launch_bounds__(256, 4)
void knn_kernel(const ushort* __restrict__ phl, const float* __restrict__ sq,
                ushort* __restrict__ cand) {
  __shared__ ushort Bt[128 * 128];  // 32 KB; aliased KT[32][128] / KT2[32][64] between passes
  __shared__ float TH[32];
  __shared__ int CNT[32];
  __shared__ ushort QU[32][QCAP];

  int t = threadIdx.x;
  int lane = t & 63;
  int w = t >> 6;
  int b = blockIdx.x >> 9;
  int seg = (blockIdx.x >> 8) & 1;
  int row0 = (blockIdx.x & 255) * 32;
  const ushort* pb = phl + (size_t)b * NPTS * 128;
  const float* sqb = sq + b * NPTS;

  int c15 = lane & 15, l4 = lane >> 4;
  int ccol = w * 32;

  // A fragments [hl][kk][rg], rows row0 + rg*16 + c15, sign-flipped (exact)
  short8 a[2][2][2];
  #pragma unroll
  for (int rg = 0; rg < 2; ++rg) {
    int n = row0 + rg * 16 + c15;
    const ushort* pr = pb + (size_t)n * 128;
    #pragma unroll
    for (int hl = 0; hl < 2; ++hl)
      #pragma unroll
      for (int kk = 0; kk < 2; ++kk) {
        int slot = (kk * 4 + l4) ^ (n & 7);
        short8 v = *(const short8*)(pr + hl * 64 + slot * 8);
        uint4v uv = *(uint4v*)&v;
        uv ^= 0x80008000u;
        a[hl][kk][rg] = *(short8*)&uv;
      }
  }

  // ================= PASS A: per-lane top-2 per owned row (8 rows/lane) =================
  float k1[2][4], k2[2][4];
  #pragma unroll
  for (int rg = 0; rg < 2; ++rg)
    #pragma unroll
    for (int r = 0; r < 4; ++r) { k1[rg][r] = __builtin_inff(); k2[rg][r] = __builtin_inff(); }

  for (int tile = 0; tile < 32; ++tile) {
    int n0 = (seg * 32 + tile) * 128;
    __syncthreads();
    #pragma unroll
    for (int j = 0; j < 8; ++j) {
      const ushort* src = pb + (size_t)(n0 + w * 32 + j * 4 + (lane >> 4)) * 128 + (lane & 15) * 8;
      gload16(src, Bt + (w * 32 + j * 4) * 128);
    }
    float sqv[2];
    #pragma unroll
    for (int cf = 0; cf < 2; ++cf) sqv[cf] = sqb[n0 + ccol + cf * 16 + c15];
    __syncthreads();

    #pragma unroll
    for (int cf = 0; cf < 2; ++cf) {
      int p = ccol + cf * 16 + c15;
      const ushort* bp = Bt + p * 128;
      int sw = p & 7;
      f32x4 c0 = {sqv[cf], sqv[cf], sqv[cf], sqv[cf]};
      f32x4 c1 = c0;
      #pragma unroll
      for (int kk = 0; kk < 2; ++kk) {
        int so = ((kk * 4 + l4) ^ sw) * 8;
        short8 bh = *(const short8*)(bp + so);
        short8 bl = *(const short8*)(bp + 64 + so);
        c0 = __builtin_amdgcn_mfma_f32_16x16x32_bf16(a[0][kk][0], bh, c0, 0, 0, 0);
        c1 = __builtin_amdgcn_mfma_f32_16x16x32_bf16(a[0][kk][1], bh, c1, 0, 0, 0);
        c0 = __builtin_amdgcn_mfma_f32_16x16x32_bf16(a[0][kk][0], bl, c0, 0, 0, 0);
        c1 = __builtin_amdgcn_mfma_f32_16x16x32_bf16(a[0][kk][1], bl, c1, 0, 0, 0);
        c0 = __builtin_amdgcn_mfma_f32_16x16x32_bf16(a[1][kk][0], bh, c0, 0, 0, 0);
        c1 = __builtin_amdgcn_mfma_f32_16x16x32_bf16(a[1][kk][1], bh, c1, 0, 0, 0);
      }
      #pragma unroll
      for (int r = 0; r < 4; ++r) {
        k2[0][r] = __builtin_amdgcn_fmed3f(c0[r], k1[0][r], k2[0][r]);
        k1[0][r] = fminf(c0[r], k1[0][r]);
        k2[1][r] = __builtin_amdgcn_fmed3f(c1[r], k1[1][r], k2[1][r]);
        k1[1][r] = fminf(c1[r], k1[1][r]);
      }
    }
  }

  // ================= subset: KT[32][128], then pair-merge to KT2[32][64] =================
  __syncthreads();
  float* KT = (float*)Bt;                 // [32][128], bytes 0..16K
  #pragma unroll
  for (int rg = 0; rg < 2; ++rg)
    #pragma unroll
    for (int r = 0; r < 4; ++r) {
      int row = rg * 16 + l4 * 4 + r;
      KT[row * 128 + (w * 16 + c15) * 2] = k1[rg][r];
      KT[row * 128 + (w * 16 + c15) * 2 + 1] = k2[rg][r];
    }
  __syncthreads();
  float* KT2 = (float*)Bt + 32 * 128;     // [32][64], bytes 16K..24K
  #pragma unroll
  for (int it = 0; it < 4; ++it) {
    int idx = t + it * 256;               // 0..1023
    int row = idx >> 5, j = idx & 31;
    float a1 = KT[row * 128 + j * 2], a2 = KT[row * 128 + j * 2 + 1];
    float b1 = KT[row * 128 + 64 + j * 2], b2 = KT[row * 128 + 64 + j * 2 + 1];
    KT2[row * 64 + j * 2] = fminf(a1, b1);
    KT2[row * 64 + j * 2 + 1] = fminf(fmaxf(a1, b1), fminf(a2, b2));
  }
  __syncthreads();

  // ================= theta per row = 22nd smallest of 64-subset =================
  {
    int row = t >> 3;
    int j0 = (t & 7) * 8;
    const f32x4* vr4 = (const f32x4*)(KT2 + row * 64);
    float vj[8];
    *(f32x4*)vj = vr4[(t & 7) * 2];
    *(f32x4*)(vj + 4) = vr4[(t & 7) * 2 + 1];
    int rank[8];
    #pragma unroll
    for (int jj = 0; jj < 8; ++jj) rank[jj] = 0;
    for (int m4 = 0; m4 < 16; ++m4) {
      f32x4 vm = vr4[m4];
      #pragma unroll
      for (int e = 0; e < 4; ++e) {
        int m = m4 * 4 + e;
        float ve = vm[e];
        #pragma unroll
        for (int jj = 0; jj < 8; ++jj)
          rank[jj] += (ve < vj[jj] || (ve == vj[jj] && m < j0 + jj)) ? 1 : 0;
      }
    }
    #pragma unroll
    for (int jj = 0; jj < 8; ++jj)
      if (rank[jj] == THRANK) TH[row] = vj[jj];
    if (t < 32) CNT[t] = 0;
  }
  __syncthreads();
  float th[2][4];
  #pragma unroll
  for (int rg = 0; rg < 2; ++rg)
    #pragma unroll
    for (int r = 0; r < 4; ++r) th[rg][r] = TH[rg * 16 + l4 * 4 + r];

  // ================= PASS B: recompute + collect key<=theta =================
  for (int tile = 0; tile < 32; ++tile) {
    int n0 = (seg * 32 + tile) * 128;
    __syncthreads();
    #pragma unroll
    for (int j = 0; j < 8; ++j) {
      const ushort* src = pb + (size_t)(n0 + w * 32 + j * 4 + (lane >> 4)) * 128 + (lane & 15) * 8;
      gload16(src, Bt + (w * 32 + j * 4) * 128);
    }
    float sqv[2];
    #pragma unroll
    for (int cf = 0; cf < 2; ++cf) sqv[cf] = sqb[n0 + ccol + cf * 16 + c15];
    __syncthreads();

    #pragma unroll
    for (int cf = 0; cf < 2; ++cf) {
      int p = ccol + cf * 16 + c15;
      const ushort* bp = Bt + p * 128;
      int sw = p & 7;
      f32x4 c0 = {sqv[cf], sqv[cf], sqv[cf], sqv[cf]};
      f32x4 c1 = c0;
      #pragma unroll
      for (int kk = 0; kk < 2; ++kk) {
        int so = ((kk * 4 + l4) ^ sw) * 8;
        short8 bh = *(const short8*)(bp + so);
        short8 bl = *(const short8*)(bp + 64 + so);
        c0 = __builtin_amdgcn_mfma_f32_16x16x32_bf16(a[0][kk][0], bh, c0, 0, 0, 0);
        c1 = __builtin_amdgcn_mfma_f32_16x16x32_bf16(a[0][kk][1], bh, c1, 0, 0, 0);
        c0 = __builtin_amdgcn_mfma_f32_16x16x32_bf16(a[0][kk][0], bl, c0, 0, 0, 0);
        c1 = __builtin_amdgcn_mfma_f32_16x16x32_bf16(a[0][kk][1], bl, c1, 0, 0, 0);
        c0 = __builtin_amdgcn_mfma_f32_16x16x32_bf16(a[1][kk][0], bh, c0, 0, 0, 0);
        c1 = __builtin_amdgcn_mfma_f32_16x16x32_bf16(a[1][kk][1], bh, c1, 0, 0, 0);
      }
      #pragma unroll
      for (int r = 0; r < 4; ++r) {
        if (c0[r] <= th[0][r]) {
          int row = l4 * 4 + r;
          int pos = atomicAdd(&CNT[row], 1);
          if (pos < QCAP) QU[row][pos] = (ushort)(n0 + p);
        }
        if (c1[r] <= th[1][r]) {
          int row = 16 + l4 * 4 + r;
          int pos = atomicAdd(&CNT[row], 1);
          if (pos < QCAP) QU[row][pos] = (ushort)(n0 + p);
        }
      }
    }
  }

  // ================= pad + dump queues =================
  __syncthreads();
  for (int i = t; i < 32 * QCAP; i += 256) {
    int row = i / QCAP, s2 = i % QCAP;
    int c2 = CNT[row]; if (c2 > QCAP) c2 = QCAP;
    ushort v = (s2 < c2) ? QU[row][s2] : (ushort)0xFFFFu;
    cand[((size_t)(b * NPTS + row0 + row) * 2 + seg) * QCAP + s2] = v;
  }
}

// ---------- exact f64 re-rank of up to 80 candidates, wave per point ----------
__global__ void refine_kernel(const float* __restrict__ pct, const ushort* __restrict__ cand,
                              int* __restrict__ knn, float* __restrict__ idxf) {
  int gw = (blockIdx.x * 256 + threadIdx.x) >> 6;  // 0..16383
  int lane = threadIdx.x & 63;
  int b = gw >> 13, n = gw & (NPTS - 1);
  const float* pcb = pct + (size_t)b * NPTS * 64;
  const ushort* cb = cand + (size_t)gw * (2 * QCAP);
  const float* qp = pcb + (size_t)n * 64;

  unsigned ciA = cb[lane];
  unsigned ciB = (lane < 2 * QCAP - 64) ? (unsigned)cb[64 + lane] : 0xFFFFu;
  double dA = __builtin_inf(), dB = __builtin_inf();
  if (ciA != 0xFFFFu) {
    const float* cp = pcb + (size_t)ciA * 64;
    double s = 0.0;
    #pragma unroll
    for (int u = 0; u < 16; ++u) {
      f32x4 cv = *(const f32x4*)(cp + u * 4);
      f32x4 qv = *(const f32x4*)(qp + u * 4);
      #pragma unroll
      for (int e = 0; e < 4; ++e) {
        double diff = (double)cv[e] - (double)qv[e];
        s = fma(diff, diff, s);
      }
    }
    dA = s;
  }
  if (ciB != 0xFFFFu) {
    const float* cp = pcb + (size_t)ciB * 64;
    double s = 0.0;
    #pragma unroll
    for (int u = 0; u < 16; ++u) {
      f32x4 cv = *(const f32x4*)(cp + u * 4);
      f32x4 qv = *(const f32x4*)(qp + u * 4);
      #pragma unroll
      for (int e = 0; e < 4; ++e) {
        double diff = (double)cv[e] - (double)qv[e];
        s = fma(diff, diff, s);
      }
    }
    dB = s;
  }

  int rA = 0, rB = 0;
  for (int j = 0; j < 64; ++j) {
    double dk = __shfl(dA, j);
    unsigned ik = (unsigned)__shfl((int)ciA, j);
    rA += ((dk < dA) || (dk == dA && ik < ciA)) ? 1 : 0;
    rB += ((dk < dB) || (dk == dB && ik < ciB)) ? 1 : 0;
  }
  for (int j = 0; j < 2 * QCAP - 64; ++j) {
    double dk = __shfl(dB, j);
    unsigned ik = (unsigned)__shfl((int)ciB, j);
    rA += ((dk < dA) || (dk == dA && ik < ciA)) ? 1 : 0;
    rB += ((dk < dB) || (dk == dB && ik < ciB)) ? 1 : 0;
  }
  if (ciA != 0xFFFFu && rA < KOUT) {
    size_t o = ((size_t)b * KOUT + rA) * NPTS + n;
    knn[o] = (int)ciA;
    idxf[o] = (float)ciA;
  }
  if (lane < 2 * QCAP - 64 && ciB != 0xFFFFu && rB < KOUT) {
    size_t o = ((size_t)b * KOUT + rB) * NPTS + n;
    knn[o] = (int)ciB;
    idxf[o] = (float)ciB;
  }
}

// ---------- edge features: out [B][128][17][N]; block = (n-chunk, b*64+c), k-loop inside ----------
__global__ __launch_bounds__(256)
void edge_kernel(const float* __restrict__ pc, const int* __restrict__ knn,
                 float* __restrict__ out) {
  int n = blockIdx.x * 256 + threadIdx.x;
  int z = blockIdx.y;
  int b = z >> 6, c = z & 63;
  const float* row = pc + ((size_t)b * DIM + c) * NPTS;
  float central = row[n];
  size_t base = (((size_t)b * 2 * DIM + c) * KOUT) * NPTS + n;
  const int* kb = knn + (size_t)b * KOUT * NPTS + n;
  #pragma unroll
  for (int k = 0; k < KOUT; ++k) {
    int nb = kb[(size_t)k * NPTS];
    float nbrv = row[nb];
    out[base + (size_t)k * NPTS] = central;
    out[base + (size_t)(DIM * KOUT + k) * NPTS] = nbrv - central;
  }
}

extern "C" void kernel_launch(void* const* d_in, const int* in_sizes, int n_in,
                              void* d_out, int out_size, void* d_ws, size_t ws_size,
                              hipStream_t stream) {
  const float* pc = (const float*)d_in[0];
  float* out = (float*)d_out;
  char* ws = (char*)d_ws;
  ushort* phl = (ushort*)ws;                                     // 4 MB
  float* pct  = (float*)(ws + (size_t)4 * 1024 * 1024);          // 4 MB
  float* sq   = (float*)(ws + (size_t)8 * 1024 * 1024);          // 64 KB
  ushort* cand = (ushort*)(ws + (size_t)8 * 1024 * 1024 + 65536);
  int* knn    = (int*)(ws + (size_t)8 * 1024 * 1024 + 65536 + (size_t)16384 * 2 * QCAP * 2);

  float* idxf = out + (size_t)BATCH * 2 * DIM * KOUT * NPTS;

  prep_kernel<<<512, 256, 0, stream>>>(pc, phl, pct, sq);
  knn_kernel<<<1024, 256, 0, stream>>>(phl, sq, cand);
  refine_kernel<<<4096, 256, 0, stream>>>(pct, cand, knn, idxf);
  edge_kernel<<<dim3(NPTS / 256, BATCH * DIM), 256, 0, stream>>>(pc, knn, out);
}